// Round 9
// baseline (197.271 us; speedup 1.0000x reference)
//
#include <hip/hip_runtime.h>
#include <math.h>

typedef float f32x4 __attribute__((ext_vector_type(4)));
typedef __bf16 bf16x8 __attribute__((ext_vector_type(8)));

#define MFMA16(a, b, c) __builtin_amdgcn_mfma_f32_16x16x32_bf16((a), (b), (c), 0, 0, 0)

__device__ __forceinline__ unsigned short f2bf(float f) {
    union { float f; unsigned u; } v; v.f = f;
    return (unsigned short)((v.u + 0x7fffu + ((v.u >> 16) & 1u)) >> 16);
}
__device__ __forceinline__ unsigned pack2(float a, float b) {
    return (unsigned)f2bf(a) | ((unsigned)f2bf(b) << 16);
}

// ---------------------------------------------------------------------------
// fp32 -> bf16 conversion of x and the 4 weight matrices. 1 float4 per thread.
// ---------------------------------------------------------------------------
__global__ __launch_bounds__(256)
void convert_bf16(const float* __restrict__ x,  const float* __restrict__ wq,
                  const float* __restrict__ wk, const float* __restrict__ wv,
                  const float* __restrict__ wo,
                  unsigned short* __restrict__ xb,  unsigned short* __restrict__ wqb,
                  unsigned short* __restrict__ wkb, unsigned short* __restrict__ wvb,
                  unsigned short* __restrict__ wob)
{
    int i = blockIdx.x * 256 + threadIdx.x;     // grid covers 1572864 float4 units
    const float* s; unsigned short* d; int o;
    if (i < 524288)       { s = x;  d = xb;  o = i; }
    else if (i < 786432)  { s = wq; d = wqb; o = i - 524288; }
    else if (i < 1048576) { s = wk; d = wkb; o = i - 786432; }
    else if (i < 1310720) { s = wv; d = wvb; o = i - 1048576; }
    else                  { s = wo; d = wob; o = i - 1310720; }
    float4 v = *reinterpret_cast<const float4*>(s + (size_t)o * 4);
    ushort4 r;
    r.x = f2bf(v.x); r.y = f2bf(v.y); r.z = f2bf(v.z); r.w = f2bf(v.w);
    *reinterpret_cast<ushort4*>(d + (size_t)o * 4) = r;
}

// ---------------------------------------------------------------------------
// C[2048,1024] = A[2048,1024] @ W[1024,1024]^T in bf16 MFMA.
// Tile 128x64, BK=64, 4 waves (2x2), wave tile 64x32.
// Register-prefetch pipeline: tile t+1 loaded to VGPRs during compute of t,
// so the vmcnt wait lands after a full compute phase (latency off crit path).
// mode 0: C bf16; mode 1: C bf16 transposed [N,M]; mode 2: C f32;
// mode 3: C bf16 scaled by (hd^-0.5 * log2(e))  [Q prescale for exp2 softmax]
// LDS XOR-swizzled (byte ^= (row&7)<<4) so frag ds_read_b128 is conflict-free.
// ---------------------------------------------------------------------------
__device__ __forceinline__ void gemm_bf16_body(const unsigned short* __restrict__ A,
                                               const unsigned short* __restrict__ W,
                                               void* __restrict__ Cp, int mode)
{
    __shared__ char Al[128 * 128];   // 128 rows x 64 bf16
    __shared__ char Bl[64 * 128];    // 64 rows x 64 bf16

    const int tid = threadIdx.x;
    const int lane = tid & 63, w = tid >> 6;
    const int g = lane >> 4, r15 = lane & 15;
    const int wm = (w >> 1) * 64, wn = (w & 1) * 32;
    const int m0 = blockIdx.y * 128, n0 = blockIdx.x * 64;

    f32x4 acc[4][2] = {};
    bf16x8 ra[4], rb[2];

    // prologue: prefetch tile 0 into regs
#pragma unroll
    for (int p = 0; p < 4; p++) {
        int idx = p * 256 + tid;
        int row = idx >> 3, c8 = idx & 7;
        ra[p] = *reinterpret_cast<const bf16x8*>(A + (size_t)(m0 + row) * 1024 + c8 * 8);
    }
#pragma unroll
    for (int p = 0; p < 2; p++) {
        int idx = p * 256 + tid;
        int row = idx >> 3, c8 = idx & 7;
        rb[p] = *reinterpret_cast<const bf16x8*>(W + (size_t)(n0 + row) * 1024 + c8 * 8);
    }

    for (int k0 = 0; k0 < 1024; k0 += 64) {
        __syncthreads();   // prev compute done reading LDS
#pragma unroll
        for (int p = 0; p < 4; p++) {
            int idx = p * 256 + tid;
            int row = idx >> 3, c8 = idx & 7;
            int byte = (row * 128 + c8 * 16) ^ ((row & 7) << 4);
            *reinterpret_cast<bf16x8*>(Al + byte) = ra[p];
        }
#pragma unroll
        for (int p = 0; p < 2; p++) {
            int idx = p * 256 + tid;
            int row = idx >> 3, c8 = idx & 7;
            int byte = (row * 128 + c8 * 16) ^ ((row & 7) << 4);
            *reinterpret_cast<bf16x8*>(Bl + byte) = rb[p];
        }
        if (k0 + 64 < 1024) {   // prefetch next tile (in flight during compute)
#pragma unroll
            for (int p = 0; p < 4; p++) {
                int idx = p * 256 + tid;
                int row = idx >> 3, c8 = idx & 7;
                ra[p] = *reinterpret_cast<const bf16x8*>(A + (size_t)(m0 + row) * 1024 + k0 + 64 + c8 * 8);
            }
#pragma unroll
            for (int p = 0; p < 2; p++) {
                int idx = p * 256 + tid;
                int row = idx >> 3, c8 = idx & 7;
                rb[p] = *reinterpret_cast<const bf16x8*>(W + (size_t)(n0 + row) * 1024 + k0 + 64 + c8 * 8);
            }
        }
        __syncthreads();
#pragma unroll
        for (int c = 0; c < 2; c++) {
            bf16x8 af[4], bfr[2];
#pragma unroll
            for (int m = 0; m < 4; m++) {
                int row = wm + m * 16 + r15;
                int byte = (row * 128 + g * 16 + c * 64) ^ ((row & 7) << 4);
                af[m] = *reinterpret_cast<const bf16x8*>(Al + byte);
            }
#pragma unroll
            for (int n = 0; n < 2; n++) {
                int row = wn + n * 16 + r15;
                int byte = (row * 128 + g * 16 + c * 64) ^ ((row & 7) << 4);
                bfr[n] = *reinterpret_cast<const bf16x8*>(Bl + byte);
            }
#pragma unroll
            for (int m = 0; m < 4; m++)
#pragma unroll
                for (int n = 0; n < 2; n++)
                    acc[m][n] = MFMA16(af[m], bfr[n], acc[m][n]);
        }
    }

    if (mode == 0 || mode == 3) {
        const float cs = (mode == 3) ? 0.25504190132624806f : 1.0f;  // 32^-0.5 * log2(e)
        unsigned short* C = (unsigned short*)Cp;
#pragma unroll
        for (int m = 0; m < 4; m++)
#pragma unroll
            for (int n = 0; n < 2; n++)
#pragma unroll
                for (int i = 0; i < 4; i++)
                    C[(size_t)(m0 + wm + m * 16 + g * 4 + i) * 1024 + n0 + wn + n * 16 + r15] =
                        f2bf(acc[m][n][i] * cs);
    } else if (mode == 1) {
        unsigned short* C = (unsigned short*)Cp;   // Ct[1024][2048]
#pragma unroll
        for (int m = 0; m < 4; m++)
#pragma unroll
            for (int n = 0; n < 2; n++) {
                unsigned long long v = (unsigned long long)pack2(acc[m][n][0], acc[m][n][1])
                                     | ((unsigned long long)pack2(acc[m][n][2], acc[m][n][3]) << 32);
                *reinterpret_cast<unsigned long long*>(
                    C + (size_t)(n0 + wn + n * 16 + r15) * 2048 + m0 + wm + m * 16 + g * 4) = v;
            }
    } else {
        float* C = (float*)Cp;
#pragma unroll
        for (int m = 0; m < 4; m++)
#pragma unroll
            for (int n = 0; n < 2; n++)
#pragma unroll
                for (int i = 0; i < 4; i++)
                    C[(size_t)(m0 + wm + m * 16 + g * 4 + i) * 1024 + n0 + wn + n * 16 + r15] =
                        acc[m][n][i];
    }
}

__global__ __launch_bounds__(256)
void gemm_qkv_bf16(const unsigned short* __restrict__ xb, const unsigned short* __restrict__ wqb,
                   const unsigned short* __restrict__ wkb, const unsigned short* __restrict__ wvb,
                   unsigned short* __restrict__ Qb, unsigned short* __restrict__ Kb,
                   unsigned short* __restrict__ Vtb)
{
    int z = blockIdx.z;
    const unsigned short* W = (z == 0) ? wqb : (z == 1) ? wkb : wvb;
    void* C = (z == 0) ? (void*)Qb : (z == 1) ? (void*)Kb : (void*)Vtb;
    gemm_bf16_body(xb, W, C, (z == 2) ? 1 : (z == 0 ? 3 : 0));
}

__global__ __launch_bounds__(256)
void gemm_out_bf16(const unsigned short* __restrict__ Nb, const unsigned short* __restrict__ wob,
                   float* __restrict__ out)
{
    gemm_bf16_body(Nb, wob, out, 2);
}

// ---------------------------------------------------------------------------
// Differential attention v4: 1 wave per block, QB=16, no K/V LDS, no barriers.
// K and V MFMA fragments are loaded DIRECTLY from global (L2-resident:
// K/V per head = 256KB; 2 heads per XCD by construction). Only P uses a
// 4KB wave-private LDS buffer. Grid 2048 = 128 q-blocks (LPT order, largest
// first) x 16 heads (h in low 4 bits -> head/XCD affinity).
// ---------------------------------------------------------------------------
__global__ __launch_bounds__(64, 3)
void attn_mfma3(const unsigned short* __restrict__ Qb, const unsigned short* __restrict__ Kb,
                const unsigned short* __restrict__ Vtb, unsigned short* __restrict__ Nb,
                const float* __restrict__ lq1, const float* __restrict__ lk1,
                const float* __restrict__ lq2, const float* __restrict__ lk2,
                const float* __restrict__ gamma)
{
    __shared__ char Pl[2][16 * 128];   // [sub][q-row 0..15][64 keys bf16], swizzled

    const int lane = threadIdx.x;
    const int g = lane >> 4, r15 = lane & 15;
    const int u = blockIdx.x >> 4, h = blockIdx.x & 15;
    const int qb = 127 - u;                 // LPT: biggest q-blocks dispatched first
    const int q0 = qb * 16;
    const int row_g = q0 + r15;             // this lane's q-row

    float s1 = 0.f, s2 = 0.f;
#pragma unroll
    for (int i = 0; i < 32; i++) { s1 += lq1[i] * lk1[i]; s2 += lq2[i] * lk2[i]; }
    const float LI = 0.4707130183435841f;          // 0.8 - 0.6*exp(-0.6)
    const float lam = expf(s1) - expf(s2) + LI;

    // Q (pre-scaled by 32^-0.5*log2e) as score-MFMA B-operand, loaded once.
    bf16x8 qf0 = *reinterpret_cast<const bf16x8*>(Qb + (size_t)row_g * 1024 + h * 64 + g * 8);
    bf16x8 qf1 = *reinterpret_cast<const bf16x8*>(Qb + (size_t)row_g * 1024 + h * 64 + 32 + g * 8);

    const unsigned short* Kh = Kb + h * 64;
    const unsigned short* Vh = Vtb + (size_t)(h * 64) * 2048;

    f32x4 oacc[2][4] = {};
    float m_u[2] = {-INFINITY, -INFINITY};   // wave-uniform running max (log2 dom)
    float l_l[2] = {0.f, 0.f};               // lane-local denominator partials

    const int nkb = (q0 + 79) >> 6;
    for (int kb = 0; kb < nkb; kb++) {
        const int j0 = kb * 64;

        // K A-fragments direct from global: row = key j0+m*16+r15, dims g*8..
        bf16x8 ka0[4], ka1[4];
#pragma unroll
        for (int m = 0; m < 4; m++) {
            const unsigned short* kp = Kh + (size_t)(j0 + m * 16 + r15) * 1024 + g * 8;
            ka0[m] = *reinterpret_cast<const bf16x8*>(kp);
            ka1[m] = *reinterpret_cast<const bf16x8*>(kp + 32);
        }
        // V B-fragments direct from global (issued early; in flight through
        // the score MFMAs and softmax): Vt row = dim n*16+r15, keys g*8+c*32.
        bf16x8 vf[4][2];
#pragma unroll
        for (int n = 0; n < 4; n++) {
            const unsigned short* vp = Vh + (size_t)(n * 16 + r15) * 2048 + j0 + g * 8;
            vf[n][0] = *reinterpret_cast<const bf16x8*>(vp);
            vf[n][1] = *reinterpret_cast<const bf16x8*>(vp + 32);
        }

        // scores: T = K . Q^T  (keys = M-frags, q-rows = N); already log2-scaled
        f32x4 sc0[4] = {}, sc1[4] = {};
#pragma unroll
        for (int m = 0; m < 4; m++) {
            sc0[m] = MFMA16(ka0[m], qf0, sc0[m]);
            sc1[m] = MFMA16(ka1[m], qf1, sc1[m]);
        }

        const bool diag = (kb == nkb - 1);    // only the last tile crosses the diagonal
#pragma unroll
        for (int s = 0; s < 2; s++) {
            f32x4* sc = s ? sc1 : sc0;
            float sv[4][4];
            float mxl = -INFINITY;
            if (diag) {
#pragma unroll
                for (int m = 0; m < 4; m++)
#pragma unroll
                    for (int i = 0; i < 4; i++) {
                        float xv = ((j0 + m * 16 + g * 4 + i) <= row_g) ? sc[m][i] : -INFINITY;
                        sv[m][i] = xv;
                        mxl = fmaxf(mxl, xv);
                    }
            } else {
#pragma unroll
                for (int m = 0; m < 4; m++)
#pragma unroll
                    for (int i = 0; i < 4; i++) {
                        sv[m][i] = sc[m][i];
                        mxl = fmaxf(mxl, sc[m][i]);
                    }
            }
            // deferred-max: rescale only when headroom (2^8) would be exceeded
            if (__any(mxl > m_u[s] + 8.0f)) {
                float wm = mxl;
                wm = fmaxf(wm, __shfl_xor(wm, 1));
                wm = fmaxf(wm, __shfl_xor(wm, 2));
                wm = fmaxf(wm, __shfl_xor(wm, 4));
                wm = fmaxf(wm, __shfl_xor(wm, 8));
                wm = fmaxf(wm, __shfl_xor(wm, 16));
                wm = fmaxf(wm, __shfl_xor(wm, 32));
                const float corr = exp2f(m_u[s] - wm);   // 0 on first tile
                m_u[s] = wm;
                l_l[s] *= corr;
#pragma unroll
                for (int n = 0; n < 4; n++)
#pragma unroll
                    for (int i = 0; i < 4; i++) oacc[s][n][i] *= corr;
            }
            float sum = 0.f;
#pragma unroll
            for (int m = 0; m < 4; m++) {
                float p0 = exp2f(sv[m][0] - m_u[s]);
                float p1 = exp2f(sv[m][1] - m_u[s]);
                float p2 = exp2f(sv[m][2] - m_u[s]);
                float p3 = exp2f(sv[m][3] - m_u[s]);
                sum += (p0 + p1) + (p2 + p3);
                unsigned long long pv = (unsigned long long)pack2(p0, p1)
                                      | ((unsigned long long)pack2(p2, p3) << 32);
                int byte = (r15 * 128 + m * 32 + g * 8) ^ ((r15 & 7) << 4);
                *reinterpret_cast<unsigned long long*>(Pl[s] + byte) = pv;
            }
            l_l[s] += sum;
        }

        // PV: O += P . V  (P A-frags from wave-private LDS; V frags from regs)
#pragma unroll
        for (int c = 0; c < 2; c++) {
            int pb = (r15 * 128 + g * 16 + c * 64) ^ ((r15 & 7) << 4);
            bf16x8 p0 = *reinterpret_cast<const bf16x8*>(Pl[0] + pb);
            bf16x8 p1 = *reinterpret_cast<const bf16x8*>(Pl[1] + pb);
#pragma unroll
            for (int n = 0; n < 4; n++) {
                oacc[0][n] = MFMA16(p0, vf[n][c], oacc[0][n]);
                oacc[1][n] = MFMA16(p1, vf[n][c], oacc[1][n]);
            }
        }
    }

    // epilogue: reduce lane-local l across the 4 key-groups (row total)
    float l0 = l_l[0];
    l0 += __shfl_xor(l0, 16); l0 += __shfl_xor(l0, 32);
    float l1 = l_l[1];
    l1 += __shfl_xor(l1, 16); l1 += __shfl_xor(l1, 32);
    const float r1 = 1.f / l0;
    const float r2 = lam / l1;
    float i1[4], i2[4];
#pragma unroll
    for (int i = 0; i < 4; i++) {
        i1[i] = __shfl(r1, g * 4 + i);
        i2[i] = __shfl(r2, g * 4 + i);
    }
    float o[4][4], ss[4] = {0.f, 0.f, 0.f, 0.f};
#pragma unroll
    for (int n = 0; n < 4; n++)
#pragma unroll
        for (int i = 0; i < 4; i++) {
            float v = oacc[0][n][i] * i1[i] - oacc[1][n][i] * i2[i];
            o[n][i] = v;
            ss[i] = fmaf(v, v, ss[i]);
        }
#pragma unroll
    for (int i = 0; i < 4; i++) {
        ss[i] += __shfl_xor(ss[i], 1);
        ss[i] += __shfl_xor(ss[i], 2);
        ss[i] += __shfl_xor(ss[i], 4);
        ss[i] += __shfl_xor(ss[i], 8);
    }
    const float post = 1.f - LI;
    float gm4[4];
#pragma unroll
    for (int n = 0; n < 4; n++) gm4[n] = gamma[n * 16 + r15];
#pragma unroll
    for (int i = 0; i < 4; i++) {
        const float rs = rsqrtf(ss[i] * 0.015625f + 1e-5f);
#pragma unroll
        for (int n = 0; n < 4; n++) {
            Nb[(size_t)(q0 + g * 4 + i) * 1024 + h * 64 + n * 16 + r15] =
                f2bf(o[n][i] * rs * gm4[n] * post);
        }
    }
}

// ---------------------------------------------------------------------------
extern "C" void kernel_launch(void* const* d_in, const int* in_sizes, int n_in,
                              void* d_out, int out_size, void* d_ws, size_t ws_size,
                              hipStream_t stream)
{
    const float* x   = (const float*)d_in[0];
    const float* Wq  = (const float*)d_in[1];
    const float* Wk  = (const float*)d_in[2];
    const float* Wv  = (const float*)d_in[3];
    const float* Wo  = (const float*)d_in[4];
    const float* lq1 = (const float*)d_in[5];
    const float* lk1 = (const float*)d_in[6];
    const float* lq2 = (const float*)d_in[7];
    const float* lk2 = (const float*)d_in[8];
    const float* gm  = (const float*)d_in[9];
    float* out = (float*)d_out;

    unsigned short* ws  = (unsigned short*)d_ws;
    unsigned short* xb  = ws;               // 2M elts
    unsigned short* wqb = xb  + 2097152;    // 1M
    unsigned short* wkb = wqb + 1048576;    // 1M
    unsigned short* wvb = wkb + 1048576;    // 1M
    unsigned short* wob = wvb + 1048576;    // 1M
    unsigned short* Qb  = wob + 1048576;    // 2M
    unsigned short* Kb  = Qb  + 2097152;    // 2M
    unsigned short* Vtb = Kb  + 2097152;    // 2M [1024 dims][2048 seq]
    unsigned short* Nb  = Vtb + 2097152;    // 2M

    convert_bf16<<<6144, 256, 0, stream>>>(x, Wq, Wk, Wv, Wo, xb, wqb, wkb, wvb, wob);
    gemm_qkv_bf16<<<dim3(16, 16, 3), 256, 0, stream>>>(xb, wqb, wkb, wvb, Qb, Kb, Vtb);
    attn_mfma3<<<2048, 64, 0, stream>>>(Qb, Kb, Vtb, Nb, lq1, lk1, lq2, lk2, gm);
    gemm_out_bf16<<<dim3(16, 16), 256, 0, stream>>>(Nb, wob, out);
}

// Round 10
// 190.044 us; speedup vs baseline: 1.0380x; 1.0380x over previous
//
#include <hip/hip_runtime.h>
#include <math.h>

typedef float f32x4 __attribute__((ext_vector_type(4)));
typedef __bf16 bf16x8 __attribute__((ext_vector_type(8)));

#define MFMA16(a, b, c) __builtin_amdgcn_mfma_f32_16x16x32_bf16((a), (b), (c), 0, 0, 0)

__device__ __forceinline__ unsigned short f2bf(float f) {
    union { float f; unsigned u; } v; v.f = f;
    return (unsigned short)((v.u + 0x7fffu + ((v.u >> 16) & 1u)) >> 16);
}
__device__ __forceinline__ unsigned pack2(float a, float b) {
    return (unsigned)f2bf(a) | ((unsigned)f2bf(b) << 16);
}
__device__ __forceinline__ unsigned cvtpk_bf16(float lo, float hi) {
    unsigned r;
    asm("v_cvt_pk_bf16_f32 %0, %1, %2" : "=v"(r) : "v"(lo), "v"(hi));
    return r;
}

// ---------------------------------------------------------------------------
// fp32 -> bf16 conversion of x and the 4 weight matrices. 1 float4 per thread.
// ---------------------------------------------------------------------------
__global__ __launch_bounds__(256)
void convert_bf16(const float* __restrict__ x,  const float* __restrict__ wq,
                  const float* __restrict__ wk, const float* __restrict__ wv,
                  const float* __restrict__ wo,
                  unsigned short* __restrict__ xb,  unsigned short* __restrict__ wqb,
                  unsigned short* __restrict__ wkb, unsigned short* __restrict__ wvb,
                  unsigned short* __restrict__ wob)
{
    int i = blockIdx.x * 256 + threadIdx.x;     // grid covers 1572864 float4 units
    const float* s; unsigned short* d; int o;
    if (i < 524288)       { s = x;  d = xb;  o = i; }
    else if (i < 786432)  { s = wq; d = wqb; o = i - 524288; }
    else if (i < 1048576) { s = wk; d = wkb; o = i - 786432; }
    else if (i < 1310720) { s = wv; d = wvb; o = i - 1048576; }
    else                  { s = wo; d = wob; o = i - 1310720; }
    float4 v = *reinterpret_cast<const float4*>(s + (size_t)o * 4);
    ushort4 r;
    r.x = f2bf(v.x); r.y = f2bf(v.y); r.z = f2bf(v.z); r.w = f2bf(v.w);
    *reinterpret_cast<ushort4*>(d + (size_t)o * 4) = r;
}

// ---------------------------------------------------------------------------
// C[2048,1024] = A[2048,1024] @ W[1024,1024]^T in bf16 MFMA.
// Tile 128x64, BK=64, 4 waves (2x2), wave tile 64x32.
// Register-prefetch pipeline (tile t+1 in VGPRs during compute of t).
// mode 0: C bf16; mode 1: C bf16 transposed [N,M]; mode 2: C f32;
// mode 3: C bf16 scaled by (hd^-0.5 * log2(e))  [Q prescale for exp2 softmax]
// LDS XOR-swizzled (byte ^= (row&7)<<4) so frag ds_read_b128 is conflict-free.
// ---------------------------------------------------------------------------
__device__ __forceinline__ void gemm_bf16_body(const unsigned short* __restrict__ A,
                                               const unsigned short* __restrict__ W,
                                               void* __restrict__ Cp, int mode)
{
    __shared__ char Al[128 * 128];   // 128 rows x 64 bf16
    __shared__ char Bl[64 * 128];    // 64 rows x 64 bf16

    const int tid = threadIdx.x;
    const int lane = tid & 63, w = tid >> 6;
    const int g = lane >> 4, r15 = lane & 15;
    const int wm = (w >> 1) * 64, wn = (w & 1) * 32;
    const int m0 = blockIdx.y * 128, n0 = blockIdx.x * 64;

    f32x4 acc[4][2] = {};
    bf16x8 ra[4], rb[2];

    // prologue: prefetch tile 0 into regs
#pragma unroll
    for (int p = 0; p < 4; p++) {
        int idx = p * 256 + tid;
        int row = idx >> 3, c8 = idx & 7;
        ra[p] = *reinterpret_cast<const bf16x8*>(A + (size_t)(m0 + row) * 1024 + c8 * 8);
    }
#pragma unroll
    for (int p = 0; p < 2; p++) {
        int idx = p * 256 + tid;
        int row = idx >> 3, c8 = idx & 7;
        rb[p] = *reinterpret_cast<const bf16x8*>(W + (size_t)(n0 + row) * 1024 + c8 * 8);
    }

    for (int k0 = 0; k0 < 1024; k0 += 64) {
        __syncthreads();   // prev compute done reading LDS
#pragma unroll
        for (int p = 0; p < 4; p++) {
            int idx = p * 256 + tid;
            int row = idx >> 3, c8 = idx & 7;
            int byte = (row * 128 + c8 * 16) ^ ((row & 7) << 4);
            *reinterpret_cast<bf16x8*>(Al + byte) = ra[p];
        }
#pragma unroll
        for (int p = 0; p < 2; p++) {
            int idx = p * 256 + tid;
            int row = idx >> 3, c8 = idx & 7;
            int byte = (row * 128 + c8 * 16) ^ ((row & 7) << 4);
            *reinterpret_cast<bf16x8*>(Bl + byte) = rb[p];
        }
        if (k0 + 64 < 1024) {   // prefetch next tile (in flight during compute)
#pragma unroll
            for (int p = 0; p < 4; p++) {
                int idx = p * 256 + tid;
                int row = idx >> 3, c8 = idx & 7;
                ra[p] = *reinterpret_cast<const bf16x8*>(A + (size_t)(m0 + row) * 1024 + k0 + 64 + c8 * 8);
            }
#pragma unroll
            for (int p = 0; p < 2; p++) {
                int idx = p * 256 + tid;
                int row = idx >> 3, c8 = idx & 7;
                rb[p] = *reinterpret_cast<const bf16x8*>(W + (size_t)(n0 + row) * 1024 + k0 + 64 + c8 * 8);
            }
        }
        __syncthreads();
#pragma unroll
        for (int c = 0; c < 2; c++) {
            bf16x8 af[4], bfr[2];
#pragma unroll
            for (int m = 0; m < 4; m++) {
                int row = wm + m * 16 + r15;
                int byte = (row * 128 + g * 16 + c * 64) ^ ((row & 7) << 4);
                af[m] = *reinterpret_cast<const bf16x8*>(Al + byte);
            }
#pragma unroll
            for (int n = 0; n < 2; n++) {
                int row = wn + n * 16 + r15;
                int byte = (row * 128 + g * 16 + c * 64) ^ ((row & 7) << 4);
                bfr[n] = *reinterpret_cast<const bf16x8*>(Bl + byte);
            }
#pragma unroll
            for (int m = 0; m < 4; m++)
#pragma unroll
                for (int n = 0; n < 2; n++)
                    acc[m][n] = MFMA16(af[m], bfr[n], acc[m][n]);
        }
    }

    if (mode == 0 || mode == 3) {
        const float cs = (mode == 3) ? 0.25504190132624806f : 1.0f;  // 32^-0.5 * log2(e)
        unsigned short* C = (unsigned short*)Cp;
#pragma unroll
        for (int m = 0; m < 4; m++)
#pragma unroll
            for (int n = 0; n < 2; n++)
#pragma unroll
                for (int i = 0; i < 4; i++)
                    C[(size_t)(m0 + wm + m * 16 + g * 4 + i) * 1024 + n0 + wn + n * 16 + r15] =
                        f2bf(acc[m][n][i] * cs);
    } else if (mode == 1) {
        unsigned short* C = (unsigned short*)Cp;   // Ct[1024][2048]
#pragma unroll
        for (int m = 0; m < 4; m++)
#pragma unroll
            for (int n = 0; n < 2; n++) {
                unsigned long long v = (unsigned long long)pack2(acc[m][n][0], acc[m][n][1])
                                     | ((unsigned long long)pack2(acc[m][n][2], acc[m][n][3]) << 32);
                *reinterpret_cast<unsigned long long*>(
                    C + (size_t)(n0 + wn + n * 16 + r15) * 2048 + m0 + wm + m * 16 + g * 4) = v;
            }
    } else {
        float* C = (float*)Cp;
#pragma unroll
        for (int m = 0; m < 4; m++)
#pragma unroll
            for (int n = 0; n < 2; n++)
#pragma unroll
                for (int i = 0; i < 4; i++)
                    C[(size_t)(m0 + wm + m * 16 + g * 4 + i) * 1024 + n0 + wn + n * 16 + r15] =
                        acc[m][n][i];
    }
}

__global__ __launch_bounds__(256)
void gemm_qkv_bf16(const unsigned short* __restrict__ xb, const unsigned short* __restrict__ wqb,
                   const unsigned short* __restrict__ wkb, const unsigned short* __restrict__ wvb,
                   unsigned short* __restrict__ Qb, unsigned short* __restrict__ Kb,
                   unsigned short* __restrict__ Vtb)
{
    int z = blockIdx.z;
    const unsigned short* W = (z == 0) ? wqb : (z == 1) ? wkb : wvb;
    void* C = (z == 0) ? (void*)Qb : (z == 1) ? (void*)Kb : (void*)Vtb;
    gemm_bf16_body(xb, W, C, (z == 2) ? 1 : (z == 0 ? 3 : 0));
}

__global__ __launch_bounds__(256)
void gemm_out_bf16(const unsigned short* __restrict__ Nb, const unsigned short* __restrict__ wob,
                   float* __restrict__ out)
{
    gemm_bf16_body(Nb, wob, out, 2);
}

// ---------------------------------------------------------------------------
// Differential attention v5: v4 structure + in-wave software pipeline.
// K register double-buffer (tile t+1 issued during tile t's softmax/PV);
// V issued at tile top, consumed at tile bottom; cvt_pk_bf16 packing.
// 1 wave per block, QB=16, no barriers. Grid 2048 = 128 q-blocks (LPT) x 16 h.
// ---------------------------------------------------------------------------
struct AttnState {
    f32x4 oacc[2][4];
    float m_u[2];
    float l_l[2];
};

__device__ __forceinline__ void attn_tile(
    int t, int nkb, int row_g, int g, int r15,
    const unsigned short* __restrict__ Kh, const unsigned short* __restrict__ Vh,
    bf16x8 (&kc0)[4], bf16x8 (&kc1)[4],      // current tile K (already loaded)
    bf16x8 (&kn0)[4], bf16x8 (&kn1)[4],      // next tile K (prefetch dest)
    const bf16x8& qf0, const bf16x8& qf1,
    AttnState& st, char* __restrict__ Pl0, char* __restrict__ Pl1)
{
    const int j0 = t * 64;

    // V loads issued first: in flight through scores+softmax, used at PV.
    bf16x8 vf[4][2];
#pragma unroll
    for (int n = 0; n < 4; n++) {
        const unsigned short* vp = Vh + (size_t)(n * 16 + r15) * 2048 + j0 + g * 8;
        vf[n][0] = *reinterpret_cast<const bf16x8*>(vp);
        vf[n][1] = *reinterpret_cast<const bf16x8*>(vp + 32);
    }

    // scores: T = K . Q^T (waits only on kc, loaded one tile ago)
    f32x4 sc0[4] = {}, sc1[4] = {};
#pragma unroll
    for (int m = 0; m < 4; m++) {
        sc0[m] = MFMA16(kc0[m], qf0, sc0[m]);
        sc1[m] = MFMA16(kc1[m], qf1, sc1[m]);
    }

    // prefetch K for tile t+1 (clamped; redundant on last tile)
    const int jn = ((t + 1 < nkb) ? t + 1 : t) * 64;
#pragma unroll
    for (int m = 0; m < 4; m++) {
        const unsigned short* kp = Kh + (size_t)(jn + m * 16 + r15) * 1024 + g * 8;
        kn0[m] = *reinterpret_cast<const bf16x8*>(kp);
        kn1[m] = *reinterpret_cast<const bf16x8*>(kp + 32);
    }

    const bool diag = (t == nkb - 1);
#pragma unroll
    for (int s = 0; s < 2; s++) {
        f32x4* sc = s ? sc1 : sc0;
        char* Pl = s ? Pl1 : Pl0;
        float sv[4][4];
        float mxl = -INFINITY;
        if (diag) {
#pragma unroll
            for (int m = 0; m < 4; m++)
#pragma unroll
                for (int i = 0; i < 4; i++) {
                    float xv = ((j0 + m * 16 + g * 4 + i) <= row_g) ? sc[m][i] : -INFINITY;
                    sv[m][i] = xv;
                    mxl = fmaxf(mxl, xv);
                }
        } else {
#pragma unroll
            for (int m = 0; m < 4; m++)
#pragma unroll
                for (int i = 0; i < 4; i++) {
                    sv[m][i] = sc[m][i];
                    mxl = fmaxf(mxl, sc[m][i]);
                }
        }
        // deferred-max: rescale only when headroom (2^8) would be exceeded
        if (__any(mxl > st.m_u[s] + 8.0f)) {
            float wm = mxl;
            wm = fmaxf(wm, __shfl_xor(wm, 1));
            wm = fmaxf(wm, __shfl_xor(wm, 2));
            wm = fmaxf(wm, __shfl_xor(wm, 4));
            wm = fmaxf(wm, __shfl_xor(wm, 8));
            wm = fmaxf(wm, __shfl_xor(wm, 16));
            wm = fmaxf(wm, __shfl_xor(wm, 32));
            const float corr = exp2f(st.m_u[s] - wm);   // 0 on first tile
            st.m_u[s] = wm;
            st.l_l[s] *= corr;
#pragma unroll
            for (int n = 0; n < 4; n++)
#pragma unroll
                for (int i = 0; i < 4; i++) st.oacc[s][n][i] *= corr;
        }
        float sum = 0.f;
#pragma unroll
        for (int m = 0; m < 4; m++) {
            float p0 = exp2f(sv[m][0] - st.m_u[s]);
            float p1 = exp2f(sv[m][1] - st.m_u[s]);
            float p2 = exp2f(sv[m][2] - st.m_u[s]);
            float p3 = exp2f(sv[m][3] - st.m_u[s]);
            sum += (p0 + p1) + (p2 + p3);
            unsigned long long pv = (unsigned long long)cvtpk_bf16(p0, p1)
                                  | ((unsigned long long)cvtpk_bf16(p2, p3) << 32);
            int byte = (r15 * 128 + m * 32 + g * 8) ^ ((r15 & 7) << 4);
            *reinterpret_cast<unsigned long long*>(Pl + byte) = pv;
        }
        st.l_l[s] += sum;
    }

    // PV: O += P . V  (P A-frags from wave-private LDS; V frags from regs)
#pragma unroll
    for (int c = 0; c < 2; c++) {
        int pb = (r15 * 128 + g * 16 + c * 64) ^ ((r15 & 7) << 4);
        bf16x8 p0 = *reinterpret_cast<const bf16x8*>(Pl0 + pb);
        bf16x8 p1 = *reinterpret_cast<const bf16x8*>(Pl1 + pb);
#pragma unroll
        for (int n = 0; n < 4; n++) {
            st.oacc[0][n] = MFMA16(p0, vf[n][c], st.oacc[0][n]);
            st.oacc[1][n] = MFMA16(p1, vf[n][c], st.oacc[1][n]);
        }
    }
}

__global__ __launch_bounds__(64, 2)
void attn_mfma4(const unsigned short* __restrict__ Qb, const unsigned short* __restrict__ Kb,
                const unsigned short* __restrict__ Vtb, unsigned short* __restrict__ Nb,
                const float* __restrict__ lq1, const float* __restrict__ lk1,
                const float* __restrict__ lq2, const float* __restrict__ lk2,
                const float* __restrict__ gamma)
{
    __shared__ char Pl[2][16 * 128];   // [sub][q-row 0..15][64 keys bf16], swizzled

    const int lane = threadIdx.x;
    const int g = lane >> 4, r15 = lane & 15;
    const int u = blockIdx.x >> 4, h = blockIdx.x & 15;
    const int qb = 127 - u;                 // LPT: biggest q-blocks dispatched first
    const int q0 = qb * 16;
    const int row_g = q0 + r15;             // this lane's q-row

    float s1 = 0.f, s2 = 0.f;
#pragma unroll
    for (int i = 0; i < 32; i++) { s1 += lq1[i] * lk1[i]; s2 += lq2[i] * lk2[i]; }
    const float LI = 0.4707130183435841f;          // 0.8 - 0.6*exp(-0.6)
    const float lam = expf(s1) - expf(s2) + LI;

    // Q (pre-scaled by 32^-0.5*log2e) as score-MFMA B-operand, loaded once.
    bf16x8 qf0 = *reinterpret_cast<const bf16x8*>(Qb + (size_t)row_g * 1024 + h * 64 + g * 8);
    bf16x8 qf1 = *reinterpret_cast<const bf16x8*>(Qb + (size_t)row_g * 1024 + h * 64 + 32 + g * 8);

    const unsigned short* Kh = Kb + h * 64;
    const unsigned short* Vh = Vtb + (size_t)(h * 64) * 2048;

    AttnState st;
#pragma unroll
    for (int s = 0; s < 2; s++) {
        st.m_u[s] = -INFINITY; st.l_l[s] = 0.f;
#pragma unroll
        for (int n = 0; n < 4; n++) st.oacc[s][n] = (f32x4){0.f, 0.f, 0.f, 0.f};
    }

    const int nkb = (q0 + 79) >> 6;

    // prologue: K tile 0 into buffer A
    bf16x8 kA0[4], kA1[4], kB0[4], kB1[4];
#pragma unroll
    for (int m = 0; m < 4; m++) {
        const unsigned short* kp = Kh + (size_t)(m * 16 + r15) * 1024 + g * 8;
        kA0[m] = *reinterpret_cast<const bf16x8*>(kp);
        kA1[m] = *reinterpret_cast<const bf16x8*>(kp + 32);
    }

    for (int kb = 0; kb < nkb; kb += 2) {
        attn_tile(kb, nkb, row_g, g, r15, Kh, Vh,
                  kA0, kA1, kB0, kB1, qf0, qf1, st, Pl[0], Pl[1]);
        if (kb + 1 < nkb)
            attn_tile(kb + 1, nkb, row_g, g, r15, Kh, Vh,
                      kB0, kB1, kA0, kA1, qf0, qf1, st, Pl[0], Pl[1]);
    }

    // epilogue: reduce lane-local l across the 4 key-groups (row total)
    float l0 = st.l_l[0];
    l0 += __shfl_xor(l0, 16); l0 += __shfl_xor(l0, 32);
    float l1 = st.l_l[1];
    l1 += __shfl_xor(l1, 16); l1 += __shfl_xor(l1, 32);
    const float r1 = 1.f / l0;
    const float r2 = lam / l1;
    float i1[4], i2[4];
#pragma unroll
    for (int i = 0; i < 4; i++) {
        i1[i] = __shfl(r1, g * 4 + i);
        i2[i] = __shfl(r2, g * 4 + i);
    }
    float o[4][4], ss[4] = {0.f, 0.f, 0.f, 0.f};
#pragma unroll
    for (int n = 0; n < 4; n++)
#pragma unroll
        for (int i = 0; i < 4; i++) {
            float v = st.oacc[0][n][i] * i1[i] - st.oacc[1][n][i] * i2[i];
            o[n][i] = v;
            ss[i] = fmaf(v, v, ss[i]);
        }
#pragma unroll
    for (int i = 0; i < 4; i++) {
        ss[i] += __shfl_xor(ss[i], 1);
        ss[i] += __shfl_xor(ss[i], 2);
        ss[i] += __shfl_xor(ss[i], 4);
        ss[i] += __shfl_xor(ss[i], 8);
    }
    const float post = 1.f - LI;
    float gm4[4];
#pragma unroll
    for (int n = 0; n < 4; n++) gm4[n] = gamma[n * 16 + r15];
#pragma unroll
    for (int i = 0; i < 4; i++) {
        const float rs = rsqrtf(ss[i] * 0.015625f + 1e-5f);
#pragma unroll
        for (int n = 0; n < 4; n++) {
            Nb[(size_t)(q0 + g * 4 + i) * 1024 + h * 64 + n * 16 + r15] =
                f2bf(o[n][i] * rs * gm4[n] * post);
        }
    }
}

// ---------------------------------------------------------------------------
extern "C" void kernel_launch(void* const* d_in, const int* in_sizes, int n_in,
                              void* d_out, int out_size, void* d_ws, size_t ws_size,
                              hipStream_t stream)
{
    const float* x   = (const float*)d_in[0];
    const float* Wq  = (const float*)d_in[1];
    const float* Wk  = (const float*)d_in[2];
    const float* Wv  = (const float*)d_in[3];
    const float* Wo  = (const float*)d_in[4];
    const float* lq1 = (const float*)d_in[5];
    const float* lk1 = (const float*)d_in[6];
    const float* lq2 = (const float*)d_in[7];
    const float* lk2 = (const float*)d_in[8];
    const float* gm  = (const float*)d_in[9];
    float* out = (float*)d_out;

    unsigned short* ws  = (unsigned short*)d_ws;
    unsigned short* xb  = ws;               // 2M elts
    unsigned short* wqb = xb  + 2097152;    // 1M
    unsigned short* wkb = wqb + 1048576;    // 1M
    unsigned short* wvb = wkb + 1048576;    // 1M
    unsigned short* wob = wvb + 1048576;    // 1M
    unsigned short* Qb  = wob + 1048576;    // 2M
    unsigned short* Kb  = Qb  + 2097152;    // 2M
    unsigned short* Vtb = Kb  + 2097152;    // 2M [1024 dims][2048 seq]
    unsigned short* Nb  = Vtb + 2097152;    // 2M

    convert_bf16<<<6144, 256, 0, stream>>>(x, Wq, Wk, Wv, Wo, xb, wqb, wkb, wvb, wob);
    gemm_qkv_bf16<<<dim3(16, 16, 3), 256, 0, stream>>>(xb, wqb, wkb, wvb, Qb, Kb, Vtb);
    attn_mfma4<<<2048, 64, 0, stream>>>(Qb, Kb, Vtb, Nb, lq1, lk1, lq2, lk2, gm);
    gemm_out_bf16<<<dim3(16, 16), 256, 0, stream>>>(Nb, wob, out);
}